// Round 5
// baseline (73.757 us; speedup 1.0000x reference)
//
#include <hip/hip_runtime.h>

// RuleBasedEmbedding round 5:
//  - prep fused into ONE single-block kernel (LDS histogram + prefix + scatter + perm)
//  - compute has ZERO LDS: b read at wave-uniform addresses (readfirstlane'd
//    base pointers -> SMEM/broadcast), M streamed per-lane from XCD-local L2.
//
// out[t][e] = sum_d base[token_ids[t]][d] * M[rule[token_ids[t]]][d][e]
// 8192 tokens, D=256, 100 rules.

#define NTOK   8192
#define NRULE  100
#define DIM    256
#define T      8                      // tokens per chunk
#define MAXCH  1152                   // >= 8192/T + NRULE (worst-case chunks)
#define LIST_SZ (NTOK + NRULE * T)

// ws int layout (COUNTS/CURSOR slots retained but unused by round-5 prep)
#define WS_COUNTS 0
#define WS_CURSOR 128
#define WS_CHRULE 256
#define WS_LIST   (WS_CHRULE + MAXCH)            // 1408
#define WS_PERM   (WS_LIST + LIST_SZ)            // 10400
#define WS_TOTAL  (WS_PERM + 8 * MAXCH)          // 19616 ints = 78464 B

// ---------------- fused prep: histogram + prefix + perm + pad + scatter ----------------
__global__ __launch_bounds__(1024)
void prep_kernel(const int* __restrict__ token_ids,
                 const int* __restrict__ token_rules, int* __restrict__ ws) {
    __shared__ int s_cnt[NRULE];
    __shared__ int s_nch[NRULE];
    __shared__ int s_poff[NRULE];
    __shared__ int s_choff[NRULE + 1];
    __shared__ int s_xbase[NRULE];
    __shared__ int s_cur[NRULE];
    const int tid = threadIdx.x;

    if (tid < NRULE) s_cnt[tid] = 0;
    __syncthreads();

    for (int t = tid; t < NTOK; t += 1024)
        atomicAdd(&s_cnt[token_rules[token_ids[t]]], 1);
    __syncthreads();

    if (tid == 0) {
        int po = 0, co = 0;
        int xc[8] = {0, 0, 0, 0, 0, 0, 0, 0};
        for (int r = 0; r < NRULE; ++r) {
            s_poff[r] = po; s_choff[r] = co;
            int n = (s_cnt[r] + T - 1) / T;
            s_nch[r] = n;
            s_xbase[r] = xc[r & 7];
            xc[r & 7] += n;
            po += n * T; co += n;
        }
        s_choff[NRULE] = co;
    }
    __syncthreads();

    if (tid < NRULE) s_cur[tid] = s_poff[tid];

    // fill perm with -1
    for (int i = tid; i < 8 * MAXCH; i += 1024) ws[WS_PERM + i] = -1;

    // pad slots in LIST (pad per rule < T)
    for (int i = tid; i < NRULE * T; i += 1024) {
        int r = i >> 3, k = i & 7;
        int pos = s_poff[r] + s_cnt[r] + k;
        if (pos < s_poff[r] + s_nch[r] * T) ws[WS_LIST + pos] = -1;
    }

    // chunk->rule map + per-XCD permutation
    const int tc = s_choff[NRULE];
    for (int c = tid; c < tc; c += 1024) {
        int lo = 0, hi = NRULE - 1;            // largest r with choff[r] <= c
        while (lo < hi) {
            int mid = (lo + hi + 1) >> 1;
            if (s_choff[mid] <= c) lo = mid; else hi = mid - 1;
        }
        ws[WS_CHRULE + c] = lo;
        ws[WS_PERM + (lo & 7) * MAXCH + s_xbase[lo] + (c - s_choff[lo])] = c;
    }
    __syncthreads();   // cursors ready before scatter

    for (int t = tid; t < NTOK; t += 1024) {
        int r = token_rules[token_ids[t]];
        int pos = atomicAdd(&s_cur[r], 1);
        ws[WS_LIST + pos] = t;
    }
}

// ---------------- compute: zero LDS, wave-uniform b, per-lane M stream ----------------
// block = 4 waves = 2 chunk-slots x 2 col-halves; each wave fully independent.
__global__ __launch_bounds__(256)
void compute_kernel(const int* __restrict__ token_ids,
                    const float* __restrict__ base_emb,
                    const float* __restrict__ rule_mats,
                    const int* __restrict__ ws,
                    float* __restrict__ out) {
    const int xcd  = blockIdx.x & 7;
    const int pair = blockIdx.x >> 3;
    const int wave = threadIdx.x >> 6, lane = threadIdx.x & 63;
    const int lc = wave >> 1, h = wave & 1;

    const int slot = pair * 2 + lc;
    const int c = __builtin_amdgcn_readfirstlane(ws[WS_PERM + xcd * MAXCH + slot]);
    if (c < 0) return;                                   // wave-uniform exit

    const int r = __builtin_amdgcn_readfirstlane(ws[WS_CHRULE + c]);

    int stk[T];
    const float* bp[T];
    #pragma unroll
    for (int t = 0; t < T; ++t) {
        stk[t] = __builtin_amdgcn_readfirstlane(ws[WS_LIST + c * T + t]);
        int id = (stk[t] >= 0) ? token_ids[stk[t]] : 0;
        id = __builtin_amdgcn_readfirstlane(id);
        bp[t] = base_emb + (size_t)id * DIM;
    }

    const float* Mp = rule_mats + (size_t)r * DIM * DIM + h * 128 + lane * 2;

    float2 acc[T];
    #pragma unroll
    for (int t = 0; t < T; ++t) acc[t] = make_float2(0.f, 0.f);

    for (int d = 0; d < DIM; d += 4) {
        const float2 m0 = *reinterpret_cast<const float2*>(Mp + (size_t)(d + 0) * DIM);
        const float2 m1 = *reinterpret_cast<const float2*>(Mp + (size_t)(d + 1) * DIM);
        const float2 m2 = *reinterpret_cast<const float2*>(Mp + (size_t)(d + 2) * DIM);
        const float2 m3 = *reinterpret_cast<const float2*>(Mp + (size_t)(d + 3) * DIM);
        #pragma unroll
        for (int t = 0; t < T; ++t) {
            const float4 b = *reinterpret_cast<const float4*>(bp[t] + d);  // wave-uniform addr
            acc[t].x += b.x * m0.x + b.y * m1.x + b.z * m2.x + b.w * m3.x;
            acc[t].y += b.x * m0.y + b.y * m1.y + b.z * m2.y + b.w * m3.y;
        }
    }

    #pragma unroll
    for (int t = 0; t < T; ++t) {
        if (stk[t] >= 0)
            *reinterpret_cast<float2*>(out + (size_t)stk[t] * DIM + h * 128 + lane * 2) = acc[t];
    }
}

// ---------------- fallback (round-1 kernel) if ws too small ----------------
__global__ __launch_bounds__(256, 4)
void rule_embed_fallback(const int* __restrict__ token_ids,
                         const float* __restrict__ base_emb,
                         const float* __restrict__ rule_mats,
                         const int* __restrict__ token_rules,
                         float* __restrict__ out, int n_tokens) {
    const int wave = threadIdx.x >> 6, lane = threadIdx.x & 63;
    const int tok = blockIdx.x * 4 + wave;
    __shared__ float base[4][DIM];
    if (tok < n_tokens) {
        const int tid = token_ids[tok];
        reinterpret_cast<float4*>(base[wave])[lane] =
            reinterpret_cast<const float4*>(base_emb + (size_t)tid * DIM)[lane];
    }
    __syncthreads();
    if (tok >= n_tokens) return;
    const int tid = token_ids[tok];
    const int r = token_rules[tid];
    const float4* M4 = reinterpret_cast<const float4*>(rule_mats + (size_t)r * DIM * DIM);
    float4 acc = make_float4(0.f, 0.f, 0.f, 0.f);
    #pragma unroll 8
    for (int d = 0; d < DIM; ++d) {
        const float b = base[wave][d];
        const float4 m = M4[d * (DIM / 4) + lane];
        acc.x += b * m.x; acc.y += b * m.y; acc.z += b * m.z; acc.w += b * m.w;
    }
    reinterpret_cast<float4*>(out + (size_t)tok * DIM)[lane] = acc;
}

extern "C" void kernel_launch(void* const* d_in, const int* in_sizes, int n_in,
                              void* d_out, int out_size, void* d_ws, size_t ws_size,
                              hipStream_t stream) {
    const int*   token_ids   = (const int*)d_in[0];    // [4, 2048]
    const float* base_emb    = (const float*)d_in[1];  // [32000, 256]
    const float* rule_mats   = (const float*)d_in[2];  // [100, 256, 256]
    const int*   token_rules = (const int*)d_in[3];    // [32000]
    float*       out         = (float*)d_out;          // [4, 2048, 256]
    int*         ws          = (int*)d_ws;

    if (ws_size < (size_t)WS_TOTAL * sizeof(int)) {
        rule_embed_fallback<<<(NTOK + 3) / 4, 256, 0, stream>>>(
            token_ids, base_emb, rule_mats, token_rules, out, NTOK);
        return;
    }

    prep_kernel<<<1, 1024, 0, stream>>>(token_ids, token_rules, ws);
    compute_kernel<<<8 * (MAXCH / 2), 256, 0, stream>>>(token_ids, base_emb, rule_mats, ws, out);
}

// Round 6
// 52.449 us; speedup vs baseline: 1.4063x; 1.4063x over previous
//
#include <hip/hip_runtime.h>

// RuleBasedEmbedding round 6: MFMA (bf16) restructure.
//   prep      : counting-sort tokens into 32-token same-rule chunks + per-XCD perm
//   convert_M : one-time f32->bf16 rule bank in MFMA B-fragment order (ws, 13.1MB)
//   gemm      : per chunk: gather+cvt A into LDS (fragment order), 8 ks x 8 MFMA/wave
//
// out[t][e] = sum_d base[token_ids[t]][d] * M[rule[token_ids[t]]][d][e]
// 8192 tokens, D=256, 100 rules.

#define NTOK   8192
#define NRULE  100
#define DIM    256
#define TCH    32                        // tokens per chunk
#define MAXCH  384                       // >= 8192/32 + 100 = 356
#define LIST_SZ (NTOK + NRULE * TCH)     // 11392

// Bfrag: [r][ks=8][ct=16][lane=64][e=8] bf16 = 100*8*16*64*8 u16 = 13,107,200 B
#define BFRAG_U16   (NRULE * 8 * 16 * 64 * 8)
#define WS_INT_BASE (BFRAG_U16 / 2)              // 3,276,800 (int index)
#define WS_CHRULE   WS_INT_BASE
#define WS_LIST     (WS_CHRULE + MAXCH)
#define WS_PERM     (WS_LIST + LIST_SZ)
#define WS_TOTAL_INT (WS_PERM + 8 * MAXCH)
#define WS_BYTES    ((size_t)WS_TOTAL_INT * 4)   // ~12.6 MB

typedef __attribute__((ext_vector_type(8))) short bf16x8;   // 8 bf16 = 4 VGPR
typedef __attribute__((ext_vector_type(4))) float f32x4;    // MFMA C/D

__device__ __forceinline__ unsigned short f2bf(float f) {
    union { float f; unsigned int u; } c; c.f = f;
    unsigned int u = c.u;
    u = (u + 0x7FFFu + ((u >> 16) & 1u)) >> 16;   // RNE
    return (unsigned short)u;
}

// ---------------- prep: histogram + prefix + perm + pad + scatter ----------------
__global__ __launch_bounds__(1024)
void prep_kernel(const int* __restrict__ token_ids,
                 const int* __restrict__ token_rules, int* __restrict__ ws) {
    __shared__ int s_cnt[NRULE];
    __shared__ int s_nch[NRULE];
    __shared__ int s_poff[NRULE];
    __shared__ int s_choff[NRULE + 1];
    __shared__ int s_xbase[NRULE];
    __shared__ int s_cur[NRULE];
    const int tid = threadIdx.x;

    if (tid < NRULE) s_cnt[tid] = 0;
    __syncthreads();

    for (int t = tid; t < NTOK; t += 1024)
        atomicAdd(&s_cnt[token_rules[token_ids[t]]], 1);
    __syncthreads();

    if (tid == 0) {
        int po = 0, co = 0;
        int xc[8] = {0, 0, 0, 0, 0, 0, 0, 0};
        for (int r = 0; r < NRULE; ++r) {
            s_poff[r] = po; s_choff[r] = co;
            int n = (s_cnt[r] + TCH - 1) / TCH;
            s_nch[r] = n;
            s_xbase[r] = xc[r & 7];
            xc[r & 7] += n;
            po += n * TCH; co += n;
        }
        s_choff[NRULE] = co;
    }
    __syncthreads();

    if (tid < NRULE) s_cur[tid] = s_poff[tid];

    // fill perm with -1
    for (int i = tid; i < 8 * MAXCH; i += 1024) ws[WS_PERM + i] = -1;
    // pad slots in LIST
    for (int i = tid; i < NRULE * TCH; i += 1024) {
        int r = i >> 5, k = i & 31;
        int pos = s_poff[r] + s_cnt[r] + k;
        if (pos < s_poff[r] + s_nch[r] * TCH) ws[WS_LIST + pos] = -1;
    }
    __syncthreads();   // perm -1 fill must complete before perm writes (round-5 race fix)

    const int tc = s_choff[NRULE];
    for (int c = tid; c < tc; c += 1024) {
        int lo = 0, hi = NRULE - 1;            // largest r with choff[r] <= c
        while (lo < hi) {
            int mid = (lo + hi + 1) >> 1;
            if (s_choff[mid] <= c) lo = mid; else hi = mid - 1;
        }
        ws[WS_CHRULE + c] = lo;
        ws[WS_PERM + (lo & 7) * MAXCH + s_xbase[lo] + (c - s_choff[lo])] = c;
    }
    __syncthreads();   // cursors + lists settled before scatter

    for (int t = tid; t < NTOK; t += 1024) {
        int r = token_rules[token_ids[t]];
        int pos = atomicAdd(&s_cur[r], 1);
        ws[WS_LIST + pos] = t;
    }
}

// ---------------- convert_M: f32 -> bf16 in B-fragment order ----------------
// block = (rule r, kstep ks): slab M[r][ks*32 .. +31][0..255].
// Bfrag[r][ks][ct][l][e] = M[r][ ks*32 + (l>>4)*8 + e ][ ct*16 + (l&15) ]
__global__ __launch_bounds__(256)
void convert_m_kernel(const float* __restrict__ M, unsigned short* __restrict__ bf) {
    const int r  = blockIdx.x >> 3;
    const int ks = blockIdx.x & 7;
    __shared__ unsigned short sb[32][DIM];    // 16 KB, row-major bf16 slab
    const int tid = threadIdx.x;

    const float4* M4 = reinterpret_cast<const float4*>(M) + ((size_t)r * 256 + ks * 32) * 64;
    #pragma unroll
    for (int j = 0; j < 8; ++j) {
        int idx = j * 256 + tid;              // 0..2047 over 32 rows x 64 float4
        int kl = idx >> 6, c4 = idx & 63;
        float4 v = M4[kl * 64 + c4];
        sb[kl][c4 * 4 + 0] = f2bf(v.x);
        sb[kl][c4 * 4 + 1] = f2bf(v.y);
        sb[kl][c4 * 4 + 2] = f2bf(v.z);
        sb[kl][c4 * 4 + 3] = f2bf(v.w);
    }
    __syncthreads();

    uint4* out = reinterpret_cast<uint4*>(bf) + ((size_t)(r * 8 + ks) * 16) * 64;
    #pragma unroll
    for (int it = 0; it < 4; ++it) {
        int w = it * 256 + tid;               // 0..1023 = 16 ct x 64 lanes
        int ct = w >> 6, l = w & 63;
        int kb = (l >> 4) * 8, cc = ct * 16 + (l & 15);
        unsigned int d0 = sb[kb + 0][cc] | ((unsigned int)sb[kb + 1][cc] << 16);
        unsigned int d1 = sb[kb + 2][cc] | ((unsigned int)sb[kb + 3][cc] << 16);
        unsigned int d2 = sb[kb + 4][cc] | ((unsigned int)sb[kb + 5][cc] << 16);
        unsigned int d3 = sb[kb + 6][cc] | ((unsigned int)sb[kb + 7][cc] << 16);
        out[ct * 64 + l] = make_uint4(d0, d1, d2, d3);
    }
}

// ---------------- gemm: chunk (32 tokens) x rule matrix via MFMA ----------------
// block = 4 waves; wave w covers cols w*64..+63 (4 ct of 16). A staged in LDS
// fragment order (gather + f32->bf16); B streamed from ws (XCD-L2-resident).
__global__ __launch_bounds__(256)
void gemm_kernel(const int* __restrict__ token_ids,
                 const float* __restrict__ base_emb,
                 const int* __restrict__ ws,
                 const unsigned short* __restrict__ bfrag,
                 float* __restrict__ out) {
    const int xcd = blockIdx.x & 7, slot = blockIdx.x >> 3;
    const int c = ws[WS_PERM + xcd * MAXCH + slot];
    if (c < 0) return;
    const int r = ws[WS_CHRULE + c];

    __shared__ unsigned short sa[8 * 2 * 64 * 8];   // 16 KB: [ks][tt][lane][e]
    __shared__ int sst[TCH];                        // token positions
    const int tid = threadIdx.x;

    if (tid < TCH) sst[tid] = ws[WS_LIST + c * TCH + tid];
    __syncthreads();

    {   // stage A: thread = (token slot s, kstep ksl); 32 k-values each
        const int s = tid >> 3, ksl = tid & 7;
        const int pos = sst[s];
        const int tt = s >> 4, lr = s & 15;
        const float4* row4 = nullptr;
        if (pos >= 0)
            row4 = reinterpret_cast<const float4*>(base_emb + (size_t)token_ids[pos] * DIM);
        #pragma unroll
        for (int j = 0; j < 8; ++j) {
            float4 v = row4 ? row4[ksl * 8 + j] : make_float4(0.f, 0.f, 0.f, 0.f);
            const int l = lr | ((j >> 1) << 4);     // k-quarter -> lane group
            const int e0 = (j & 1) * 4;
            ushort4 p;
            p.x = f2bf(v.x); p.y = f2bf(v.y); p.z = f2bf(v.z); p.w = f2bf(v.w);
            *reinterpret_cast<ushort4*>(&sa[((ksl * 2 + tt) * 64 + l) * 8 + e0]) = p;
        }
    }
    __syncthreads();

    const int wave = tid >> 6, lane = tid & 63;
    f32x4 acc[2][4];
    #pragma unroll
    for (int tt = 0; tt < 2; ++tt)
        #pragma unroll
        for (int ctl = 0; ctl < 4; ++ctl)
            acc[tt][ctl] = (f32x4){0.f, 0.f, 0.f, 0.f};

    const bf16x8* Af = reinterpret_cast<const bf16x8*>(sa);
    const bf16x8* Bf = reinterpret_cast<const bf16x8*>(bfrag) + (size_t)r * 8 * 16 * 64;

    #pragma unroll
    for (int ks = 0; ks < 8; ++ks) {
        const bf16x8 a0 = Af[(ks * 2 + 0) * 64 + lane];
        const bf16x8 a1 = Af[(ks * 2 + 1) * 64 + lane];
        const bf16x8 b0 = Bf[(ks * 16 + wave * 4 + 0) * 64 + lane];
        const bf16x8 b1 = Bf[(ks * 16 + wave * 4 + 1) * 64 + lane];
        const bf16x8 b2 = Bf[(ks * 16 + wave * 4 + 2) * 64 + lane];
        const bf16x8 b3 = Bf[(ks * 16 + wave * 4 + 3) * 64 + lane];
        acc[0][0] = __builtin_amdgcn_mfma_f32_16x16x32_bf16(a0, b0, acc[0][0], 0, 0, 0);
        acc[0][1] = __builtin_amdgcn_mfma_f32_16x16x32_bf16(a0, b1, acc[0][1], 0, 0, 0);
        acc[0][2] = __builtin_amdgcn_mfma_f32_16x16x32_bf16(a0, b2, acc[0][2], 0, 0, 0);
        acc[0][3] = __builtin_amdgcn_mfma_f32_16x16x32_bf16(a0, b3, acc[0][3], 0, 0, 0);
        acc[1][0] = __builtin_amdgcn_mfma_f32_16x16x32_bf16(a1, b0, acc[1][0], 0, 0, 0);
        acc[1][1] = __builtin_amdgcn_mfma_f32_16x16x32_bf16(a1, b1, acc[1][1], 0, 0, 0);
        acc[1][2] = __builtin_amdgcn_mfma_f32_16x16x32_bf16(a1, b2, acc[1][2], 0, 0, 0);
        acc[1][3] = __builtin_amdgcn_mfma_f32_16x16x32_bf16(a1, b3, acc[1][3], 0, 0, 0);
    }

    // D layout: col = lane&15, row = (lane>>4)*4 + reg
    #pragma unroll
    for (int tt = 0; tt < 2; ++tt) {
        #pragma unroll
        for (int reg = 0; reg < 4; ++reg) {
            const int row = tt * 16 + (lane >> 4) * 4 + reg;
            const int pos = sst[row];
            if (pos >= 0) {
                #pragma unroll
                for (int ctl = 0; ctl < 4; ++ctl) {
                    const int col = (wave * 4 + ctl) * 16 + (lane & 15);
                    out[(size_t)pos * DIM + col] = acc[tt][ctl][reg];
                }
            }
        }
    }
}

// ---------------- fallback (round-1 kernel) if ws too small ----------------
__global__ __launch_bounds__(256, 4)
void rule_embed_fallback(const int* __restrict__ token_ids,
                         const float* __restrict__ base_emb,
                         const float* __restrict__ rule_mats,
                         const int* __restrict__ token_rules,
                         float* __restrict__ out, int n_tokens) {
    const int wave = threadIdx.x >> 6, lane = threadIdx.x & 63;
    const int tok = blockIdx.x * 4 + wave;
    __shared__ float base[4][DIM];
    if (tok < n_tokens) {
        const int tid = token_ids[tok];
        reinterpret_cast<float4*>(base[wave])[lane] =
            reinterpret_cast<const float4*>(base_emb + (size_t)tid * DIM)[lane];
    }
    __syncthreads();
    if (tok >= n_tokens) return;
    const int tid = token_ids[tok];
    const int r = token_rules[tid];
    const float4* M4 = reinterpret_cast<const float4*>(rule_mats + (size_t)r * DIM * DIM);
    float4 acc = make_float4(0.f, 0.f, 0.f, 0.f);
    #pragma unroll 8
    for (int d = 0; d < DIM; ++d) {
        const float b = base[wave][d];
        const float4 m = M4[d * (DIM / 4) + lane];
        acc.x += b * m.x; acc.y += b * m.y; acc.z += b * m.z; acc.w += b * m.w;
    }
    reinterpret_cast<float4*>(out + (size_t)tok * DIM)[lane] = acc;
}

extern "C" void kernel_launch(void* const* d_in, const int* in_sizes, int n_in,
                              void* d_out, int out_size, void* d_ws, size_t ws_size,
                              hipStream_t stream) {
    const int*   token_ids   = (const int*)d_in[0];    // [4, 2048]
    const float* base_emb    = (const float*)d_in[1];  // [32000, 256]
    const float* rule_mats   = (const float*)d_in[2];  // [100, 256, 256]
    const int*   token_rules = (const int*)d_in[3];    // [32000]
    float*       out         = (float*)d_out;          // [4, 2048, 256]

    if (ws_size < WS_BYTES) {
        rule_embed_fallback<<<(NTOK + 3) / 4, 256, 0, stream>>>(
            token_ids, base_emb, rule_mats, token_rules, out, NTOK);
        return;
    }

    int*            ws = (int*)d_ws;
    unsigned short* bf = (unsigned short*)d_ws;

    prep_kernel<<<1, 1024, 0, stream>>>(token_ids, token_rules, ws);
    convert_m_kernel<<<NRULE * 8, 256, 0, stream>>>(rule_mats, bf);
    gemm_kernel<<<8 * MAXCH, 256, 0, stream>>>(token_ids, base_emb, ws, bf, out);
}

// Round 7
// 44.369 us; speedup vs baseline: 1.6624x; 1.1821x over previous
//
#include <hip/hip_runtime.h>

// RuleBasedEmbedding round 7:
//   prep_convert : ONE launch; blocks 0..799 convert M f32->bf16 (B-fragment
//                  order), block 800 runs the pipelined counting-sort prep
//                  (16-deep batched gathers, rules kept in registers).
//   gemm         : compacted grid (8 XCD x 96 blocks, 4-slot stride loop);
//                  per chunk: gather+cvt A into LDS, 8 ks x 8 MFMA/wave.
//
// out[t][e] = sum_d base[token_ids[t]][d] * M[rule[token_ids[t]]][d][e]
// 8192 tokens, D=256, 100 rules.

#define NTOK   8192
#define NRULE  100
#define DIM    256
#define TCH    32                        // tokens per chunk
#define MAXCH  384                       // >= 8192/32 + 100 = 356
#define GSTR   96                        // gemm blocks per XCD (x4 slots each)
#define LIST_SZ (NTOK + NRULE * TCH)     // 11392

// Bfrag: [r][ks=8][ct=16][lane=64][e=8] bf16 = 13,107,200 B
#define BFRAG_U16   (NRULE * 8 * 16 * 64 * 8)
#define WS_INT_BASE (BFRAG_U16 / 2)
#define WS_CHRULE   WS_INT_BASE
#define WS_LIST     (WS_CHRULE + MAXCH)
#define WS_PERM     (WS_LIST + LIST_SZ)
#define WS_TOTAL_INT (WS_PERM + 8 * MAXCH)
#define WS_BYTES    ((size_t)WS_TOTAL_INT * 4)   // ~12.6 MB

typedef __attribute__((ext_vector_type(8))) short bf16x8;   // 8 bf16 = 4 VGPR
typedef __attribute__((ext_vector_type(4))) float f32x4;    // MFMA C/D

__device__ __forceinline__ unsigned short f2bf(float f) {
    union { float f; unsigned int u; } c; c.f = f;
    unsigned int u = c.u;
    u = (u + 0x7FFFu + ((u >> 16) & 1u)) >> 16;   // RNE
    return (unsigned short)u;
}

// ---------------- fused prep + convert ----------------
// blocks 0..NRULE*8-1: convert slab M[r][ks*32..+31][:] -> Bfrag
// block NRULE*8: prep (histogram + prefix + perm + pad + scatter), 256 thr
__global__ __launch_bounds__(256)
void prep_convert_kernel(const int* __restrict__ token_ids,
                         const int* __restrict__ token_rules,
                         const float* __restrict__ M,
                         int* __restrict__ ws,
                         unsigned short* __restrict__ bf) {
    const int tid = threadIdx.x;

    if (blockIdx.x < NRULE * 8) {
        // ---- convert slab ----
        const int r  = blockIdx.x >> 3;
        const int ks = blockIdx.x & 7;
        __shared__ unsigned short sb[32][DIM];    // 16 KB row-major bf16 slab

        const float4* M4 = reinterpret_cast<const float4*>(M) + ((size_t)r * 256 + ks * 32) * 64;
        #pragma unroll
        for (int j = 0; j < 8; ++j) {
            int idx = j * 256 + tid;              // 32 rows x 64 float4
            int kl = idx >> 6, c4 = idx & 63;
            float4 v = M4[kl * 64 + c4];
            sb[kl][c4 * 4 + 0] = f2bf(v.x);
            sb[kl][c4 * 4 + 1] = f2bf(v.y);
            sb[kl][c4 * 4 + 2] = f2bf(v.z);
            sb[kl][c4 * 4 + 3] = f2bf(v.w);
        }
        __syncthreads();

        // Bfrag[r][ks][ct][l][e] = M[r][ks*32 + (l>>4)*8 + e][ct*16 + (l&15)]
        uint4* outp = reinterpret_cast<uint4*>(bf) + ((size_t)(r * 8 + ks) * 16) * 64;
        #pragma unroll
        for (int it = 0; it < 4; ++it) {
            int w = it * 256 + tid;               // 16 ct x 64 lanes
            int ct = w >> 6, l = w & 63;
            int kb = (l >> 4) * 8, cc = ct * 16 + (l & 15);
            unsigned int d0 = sb[kb + 0][cc] | ((unsigned int)sb[kb + 1][cc] << 16);
            unsigned int d1 = sb[kb + 2][cc] | ((unsigned int)sb[kb + 3][cc] << 16);
            unsigned int d2 = sb[kb + 4][cc] | ((unsigned int)sb[kb + 5][cc] << 16);
            unsigned int d3 = sb[kb + 6][cc] | ((unsigned int)sb[kb + 7][cc] << 16);
            outp[ct * 64 + l] = make_uint4(d0, d1, d2, d3);
        }
        return;
    }

    // ---- prep (one block, 256 threads, 32 tokens/thread) ----
    __shared__ int s_cnt[NRULE];
    __shared__ int s_nch[NRULE];
    __shared__ int s_poff[NRULE];
    __shared__ int s_choff[NRULE + 1];
    __shared__ int s_xbase[NRULE];
    __shared__ int s_cur[NRULE];

    if (tid < NRULE) s_cnt[tid] = 0;
    __syncthreads();

    int rul[32];                                  // rules kept for scatter phase
    #pragma unroll
    for (int half = 0; half < 2; ++half) {
        int ids[16];
        #pragma unroll
        for (int j = 0; j < 16; ++j)              // 16 independent id loads
            ids[j] = token_ids[(half * 16 + j) * 256 + tid];
        #pragma unroll
        for (int j = 0; j < 16; ++j)              // 16 independent rule gathers
            rul[half * 16 + j] = token_rules[ids[j]];
    }
    #pragma unroll
    for (int j = 0; j < 32; ++j) atomicAdd(&s_cnt[rul[j]], 1);
    __syncthreads();

    if (tid == 0) {
        int po = 0, co = 0;
        int xc[8] = {0, 0, 0, 0, 0, 0, 0, 0};
        for (int r = 0; r < NRULE; ++r) {
            s_poff[r] = po; s_choff[r] = co;
            int n = (s_cnt[r] + TCH - 1) / TCH;
            s_nch[r] = n;
            s_xbase[r] = xc[r & 7];
            xc[r & 7] += n;
            po += n * TCH; co += n;
        }
        s_choff[NRULE] = co;
    }
    __syncthreads();

    if (tid < NRULE) s_cur[tid] = s_poff[tid];
    for (int i = tid; i < 8 * MAXCH; i += 256) ws[WS_PERM + i] = -1;
    for (int i = tid; i < NRULE * TCH; i += 256) {       // pad slots
        int r = i >> 5, k = i & 31;
        int pos = s_poff[r] + s_cnt[r] + k;
        if (pos < s_poff[r] + s_nch[r] * TCH) ws[WS_LIST + pos] = -1;
    }
    __syncthreads();   // -1 fills + s_cur visible before perm writes & scatter

    const int tc = s_choff[NRULE];
    for (int c = tid; c < tc; c += 256) {
        int lo = 0, hi = NRULE - 1;            // largest r with choff[r] <= c
        while (lo < hi) {
            int mid = (lo + hi + 1) >> 1;
            if (s_choff[mid] <= c) lo = mid; else hi = mid - 1;
        }
        ws[WS_CHRULE + c] = lo;
        ws[WS_PERM + (lo & 7) * MAXCH + s_xbase[lo] + (c - s_choff[lo])] = c;
    }

    #pragma unroll
    for (int j = 0; j < 32; ++j) {             // scatter: no re-gather (rul[] cached)
        int pos = atomicAdd(&s_cur[rul[j]], 1);
        ws[WS_LIST + pos] = j * 256 + tid;
    }
}

// ---------------- gemm: chunk (32 tokens) x rule matrix via MFMA ----------------
// 8 XCD classes x GSTR blocks; each block strides 4 slots of its XCD's
// compacted perm list (tail all -1 -> uniform early exit).
__global__ __launch_bounds__(256)
void gemm_kernel(const int* __restrict__ token_ids,
                 const float* __restrict__ base_emb,
                 const int* __restrict__ ws,
                 const unsigned short* __restrict__ bfrag,
                 float* __restrict__ out) {
    const int xcd  = blockIdx.x & 7;
    const int base = blockIdx.x >> 3;               // 0..GSTR-1
    const int tid  = threadIdx.x;
    const int wave = tid >> 6, lane = tid & 63;

    __shared__ unsigned short sa[8 * 2 * 64 * 8];   // 16 KB: [ks][tt][lane][e]
    __shared__ int sst[TCH];

    for (int slot = base; slot < MAXCH; slot += GSTR) {
        const int c = ws[WS_PERM + xcd * MAXCH + slot];
        if (c < 0) return;                          // compacted: uniform exit
        const int r = ws[WS_CHRULE + c];

        __syncthreads();                            // sa/sst safe to overwrite
        if (tid < TCH) sst[tid] = ws[WS_LIST + c * TCH + tid];
        __syncthreads();

        {   // stage A: thread = (token slot s, kstep ksl)
            const int s = tid >> 3, ksl = tid & 7;
            const int pos = sst[s];
            const int tt = s >> 4, lr = s & 15;
            const float4* row4 = nullptr;
            if (pos >= 0)
                row4 = reinterpret_cast<const float4*>(base_emb + (size_t)token_ids[pos] * DIM);
            #pragma unroll
            for (int j = 0; j < 8; ++j) {
                float4 v = row4 ? row4[ksl * 8 + j] : make_float4(0.f, 0.f, 0.f, 0.f);
                const int l = lr | ((j >> 1) << 4);
                const int e0 = (j & 1) * 4;
                ushort4 p;
                p.x = f2bf(v.x); p.y = f2bf(v.y); p.z = f2bf(v.z); p.w = f2bf(v.w);
                *reinterpret_cast<ushort4*>(&sa[((ksl * 2 + tt) * 64 + l) * 8 + e0]) = p;
            }
        }
        __syncthreads();

        f32x4 acc[2][4];
        #pragma unroll
        for (int tt = 0; tt < 2; ++tt)
            #pragma unroll
            for (int ctl = 0; ctl < 4; ++ctl)
                acc[tt][ctl] = (f32x4){0.f, 0.f, 0.f, 0.f};

        const bf16x8* Af = reinterpret_cast<const bf16x8*>(sa);
        const bf16x8* Bf = reinterpret_cast<const bf16x8*>(bfrag) + (size_t)r * 8 * 16 * 64;

        #pragma unroll
        for (int ks = 0; ks < 8; ++ks) {
            const bf16x8 a0 = Af[(ks * 2 + 0) * 64 + lane];
            const bf16x8 a1 = Af[(ks * 2 + 1) * 64 + lane];
            const bf16x8 b0 = Bf[(ks * 16 + wave * 4 + 0) * 64 + lane];
            const bf16x8 b1 = Bf[(ks * 16 + wave * 4 + 1) * 64 + lane];
            const bf16x8 b2 = Bf[(ks * 16 + wave * 4 + 2) * 64 + lane];
            const bf16x8 b3 = Bf[(ks * 16 + wave * 4 + 3) * 64 + lane];
            acc[0][0] = __builtin_amdgcn_mfma_f32_16x16x32_bf16(a0, b0, acc[0][0], 0, 0, 0);
            acc[0][1] = __builtin_amdgcn_mfma_f32_16x16x32_bf16(a0, b1, acc[0][1], 0, 0, 0);
            acc[0][2] = __builtin_amdgcn_mfma_f32_16x16x32_bf16(a0, b2, acc[0][2], 0, 0, 0);
            acc[0][3] = __builtin_amdgcn_mfma_f32_16x16x32_bf16(a0, b3, acc[0][3], 0, 0, 0);
            acc[1][0] = __builtin_amdgcn_mfma_f32_16x16x32_bf16(a1, b0, acc[1][0], 0, 0, 0);
            acc[1][1] = __builtin_amdgcn_mfma_f32_16x16x32_bf16(a1, b1, acc[1][1], 0, 0, 0);
            acc[1][2] = __builtin_amdgcn_mfma_f32_16x16x32_bf16(a1, b2, acc[1][2], 0, 0, 0);
            acc[1][3] = __builtin_amdgcn_mfma_f32_16x16x32_bf16(a1, b3, acc[1][3], 0, 0, 0);
        }

        // D layout: col = lane&15, row = (lane>>4)*4 + reg
        #pragma unroll
        for (int tt = 0; tt < 2; ++tt) {
            #pragma unroll
            for (int reg = 0; reg < 4; ++reg) {
                const int row = tt * 16 + (lane >> 4) * 4 + reg;
                const int pos = sst[row];
                if (pos >= 0) {
                    #pragma unroll
                    for (int ctl = 0; ctl < 4; ++ctl) {
                        const int col = (wave * 4 + ctl) * 16 + (lane & 15);
                        out[(size_t)pos * DIM + col] = acc[tt][ctl][reg];
                    }
                }
            }
        }
    }
}

// ---------------- fallback (round-1 kernel) if ws too small ----------------
__global__ __launch_bounds__(256, 4)
void rule_embed_fallback(const int* __restrict__ token_ids,
                         const float* __restrict__ base_emb,
                         const float* __restrict__ rule_mats,
                         const int* __restrict__ token_rules,
                         float* __restrict__ out, int n_tokens) {
    const int wave = threadIdx.x >> 6, lane = threadIdx.x & 63;
    const int tok = blockIdx.x * 4 + wave;
    __shared__ float base[4][DIM];
    if (tok < n_tokens) {
        const int tid = token_ids[tok];
        reinterpret_cast<float4*>(base[wave])[lane] =
            reinterpret_cast<const float4*>(base_emb + (size_t)tid * DIM)[lane];
    }
    __syncthreads();
    if (tok >= n_tokens) return;
    const int tid = token_ids[tok];
    const int r = token_rules[tid];
    const float4* M4 = reinterpret_cast<const float4*>(rule_mats + (size_t)r * DIM * DIM);
    float4 acc = make_float4(0.f, 0.f, 0.f, 0.f);
    #pragma unroll 8
    for (int d = 0; d < DIM; ++d) {
        const float b = base[wave][d];
        const float4 m = M4[d * (DIM / 4) + lane];
        acc.x += b * m.x; acc.y += b * m.y; acc.z += b * m.z; acc.w += b * m.w;
    }
    reinterpret_cast<float4*>(out + (size_t)tok * DIM)[lane] = acc;
}

extern "C" void kernel_launch(void* const* d_in, const int* in_sizes, int n_in,
                              void* d_out, int out_size, void* d_ws, size_t ws_size,
                              hipStream_t stream) {
    const int*   token_ids   = (const int*)d_in[0];    // [4, 2048]
    const float* base_emb    = (const float*)d_in[1];  // [32000, 256]
    const float* rule_mats   = (const float*)d_in[2];  // [100, 256, 256]
    const int*   token_rules = (const int*)d_in[3];    // [32000]
    float*       out         = (float*)d_out;          // [4, 2048, 256]

    if (ws_size < WS_BYTES) {
        rule_embed_fallback<<<(NTOK + 3) / 4, 256, 0, stream>>>(
            token_ids, base_emb, rule_mats, token_rules, out, NTOK);
        return;
    }

    int*            ws = (int*)d_ws;
    unsigned short* bf = (unsigned short*)d_ws;

    prep_convert_kernel<<<NRULE * 8 + 1, 256, 0, stream>>>(
        token_ids, token_rules, rule_mats, ws, bf);
    gemm_kernel<<<8 * GSTR, 256, 0, stream>>>(token_ids, base_emb, ws, bf, out);
}